// Round 8
// baseline (83.663 us; speedup 1.0000x reference)
//
#include <hip/hip_runtime.h>
#include <math.h>

#define BATCH 32
#define HW (512*512)
#define NCHUNK 4096        // HW / 64 positions per chunk
#define PADK 72            // shorts per LDS row (64 data + 8 pad)
#define WLDS (32*PADK)     // shorts per array per wave
#define SLICE 1184         // G[1024] + 5*32 row sums
#define RED2N 9472         // 8*1184 second-level partials

typedef __attribute__((ext_vector_type(8))) short bf16x8;
typedef __attribute__((ext_vector_type(4))) float f32x4;

__device__ __forceinline__ float fsigmoid(float x) {
    float e = __builtin_amdgcn_exp2f(-x * 1.44269504088896340736f);
    return __builtin_amdgcn_rcpf(1.0f + e);
}

// pack two f32 -> two bf16 (RNE) in one uint
__device__ __forceinline__ unsigned pkbf(float a, float b) {
    unsigned ua = __float_as_uint(a);
    ua = (ua + 0x7fffu + ((ua >> 16) & 1u)) >> 16;
    unsigned ub = __float_as_uint(b);
    ub = (ub + 0x7fffu + ((ub >> 16) & 1u)) & 0xffff0000u;
    return ua | ub;
}

__global__ __launch_bounds__(256, 4) void cos_loss_main(
    const float* __restrict__ x1, const float* __restrict__ x2,
    const float* __restrict__ mk, float* __restrict__ ws, int ns)
{
    __shared__ __align__(16) short smem[4 * 2 * WLDS];   // 36864 B

    const int t = threadIdx.x;
    const int w = t >> 6;
    const int l = t & 63;

    if (blockIdx.x == 0 && t == 0) {
        unsigned* cnt = (unsigned*)(ws + (size_t)ns * SLICE + RED2N);
        *cnt = 0u;   // visible to tail kernel via kernel-boundary ordering
    }

    short* S1 = smem + w * (2 * WLDS);
    short* S2 = S1 + WLDS;

    const int row = l >> 1;          // 0..31 (phase A row)
    const int ph  = (l & 1) * 32;    // position half within chunk
    const int q   = l >> 4;          // MFMA k-group 0..3
    const int fr  = l & 15;          // MFMA frag row/col

    f32x4 acc00 = {0.f,0.f,0.f,0.f}, acc01 = {0.f,0.f,0.f,0.f};
    f32x4 acc10 = {0.f,0.f,0.f,0.f}, acc11 = {0.f,0.f,0.f,0.f};
    float n1 = 0.f, n2 = 0.f, pp = 0.f, p1 = 0.f, p2 = 0.f;

    for (int chunk = blockIdx.x * 4 + w; chunk < NCHUNK; chunk += ns * 4) {
        const unsigned base = (unsigned)row * HW + (unsigned)chunk * 64 + ph;

        // ---- Phase A: load fp32, sigmoid^2, fused row sums, bf16 -> wave-private LDS
        #pragma unroll 2
        for (int j = 0; j < 8; ++j) {
            float4 v1 = *(const float4*)(x1 + base + j * 4);
            float4 v2 = *(const float4*)(x2 + base + j * 4);
            float4 vm = *(const float4*)(mk + base + j * 4);
            float4 q1, q2;
            { float s = fsigmoid(v1.x); q1.x = s*s; }
            { float s = fsigmoid(v1.y); q1.y = s*s; }
            { float s = fsigmoid(v1.z); q1.z = s*s; }
            { float s = fsigmoid(v1.w); q1.w = s*s; }
            { float s = fsigmoid(v2.x); q2.x = s*s; }
            { float s = fsigmoid(v2.y); q2.y = s*s; }
            { float s = fsigmoid(v2.z); q2.z = s*s; }
            { float s = fsigmoid(v2.w); q2.w = s*s; }
            n1 += (q1.x + q1.y) + (q1.z + q1.w);
            n2 += (q2.x + q2.y) + (q2.z + q2.w);
            p1 = fmaf(vm.x, q1.x, fmaf(vm.y, q1.y, fmaf(vm.z, q1.z, fmaf(vm.w, q1.w, p1))));
            p2 = fmaf(vm.x, q2.x, fmaf(vm.y, q2.y, fmaf(vm.z, q2.z, fmaf(vm.w, q2.w, p2))));
            pp = fmaf(vm.x, q1.x*q2.x, fmaf(vm.y, q1.y*q2.y,
                 fmaf(vm.z, q1.z*q2.z, fmaf(vm.w, q1.w*q2.w, pp))));
            uint2 u1; u1.x = pkbf(q1.x, q1.y); u1.y = pkbf(q1.z, q1.w);
            uint2 u2; u2.x = pkbf(q2.x, q2.y); u2.y = pkbf(q2.z, q2.w);
            *(uint2*)(S1 + row * PADK + ph + j * 4) = u1;
            *(uint2*)(S2 + row * PADK + ph + j * 4) = u2;
        }

        // ---- Phase B: 2x2 tiles of 16x16x32 bf16 MFMA over K=64
        // A,B frags use identical row-major addressing -> k-permutation cancels.
        #pragma unroll
        for (int ks = 0; ks < 2; ++ks) {
            bf16x8 a0 = *(const bf16x8*)(S1 + (fr     ) * PADK + ks * 32 + q * 8);
            bf16x8 a1 = *(const bf16x8*)(S1 + (16 + fr) * PADK + ks * 32 + q * 8);
            bf16x8 b0 = *(const bf16x8*)(S2 + (fr     ) * PADK + ks * 32 + q * 8);
            bf16x8 b1 = *(const bf16x8*)(S2 + (16 + fr) * PADK + ks * 32 + q * 8);
            acc00 = __builtin_amdgcn_mfma_f32_16x16x32_bf16(a0, b0, acc00, 0, 0, 0);
            acc01 = __builtin_amdgcn_mfma_f32_16x16x32_bf16(a0, b1, acc01, 0, 0, 0);
            acc10 = __builtin_amdgcn_mfma_f32_16x16x32_bf16(a1, b0, acc10, 0, 0, 0);
            acc11 = __builtin_amdgcn_mfma_f32_16x16x32_bf16(a1, b1, acc11, 0, 0, 0);
        }
    }

    // ---- combine row-sum halves (lanes 2r, 2r+1 share row r)
    n1 += __shfl_xor(n1, 1);
    n2 += __shfl_xor(n2, 1);
    pp += __shfl_xor(pp, 1);
    p1 += __shfl_xor(p1, 1);
    p2 += __shfl_xor(p2, 1);

    // ---- cross-wave merge via LDS (staging buffers now dead)
    __syncthreads();
    float* Gm = (float*)smem;          // [4][1024]
    float* Rm = (float*)smem + 4096;   // [4][160]
    {
        const int gb = w * 1024;
        #pragma unroll
        for (int r2 = 0; r2 < 4; ++r2) {
            // C/D layout (m89): col = lane&15, row = (lane>>4)*4 + reg
            Gm[gb + (     q*4 + r2) * 32 +      fr] = acc00[r2];
            Gm[gb + (     q*4 + r2) * 32 + 16 + fr] = acc01[r2];
            Gm[gb + (16 + q*4 + r2) * 32 +      fr] = acc10[r2];
            Gm[gb + (16 + q*4 + r2) * 32 + 16 + fr] = acc11[r2];
        }
        if ((l & 1) == 0) {
            const int rb = w * 160;
            Rm[rb +       row] = n1;
            Rm[rb +  32 + row] = n2;
            Rm[rb +  64 + row] = pp;
            Rm[rb +  96 + row] = p1;
            Rm[rb + 128 + row] = p2;
        }
    }
    __syncthreads();

    float* slice = ws + (size_t)blockIdx.x * SLICE;
    #pragma unroll
    for (int r2 = 0; r2 < 4; ++r2) {
        int e = r2 * 256 + t;
        slice[e] = ((Gm[e] + Gm[1024 + e]) + (Gm[2048 + e] + Gm[3072 + e]));
    }
    if (t < 160)
        slice[1024 + t] = ((Rm[t] + Rm[160 + t]) + (Rm[320 + t] + Rm[480 + t]));
}

// grid (37, 8): block (ib, kc) sums slices k in [kc*ns/8,(kc+1)*ns/8) for
// 32 elements; last-done block reduces the 8 partials and runs the epilogue.
__global__ __launch_bounds__(256) void cos_loss_tail(
    float* __restrict__ ws, int ns, float* __restrict__ out)
{
    float* red2 = ws + (size_t)ns * SLICE;          // [8][1184]
    unsigned* cnt = (unsigned*)(red2 + RED2N);

    const int t  = threadIdx.x;
    const int ib = blockIdx.x;     // 0..36
    const int kc = blockIdx.y;     // 0..7
    const int e  = ib * 32 + (t & 31);
    const int kq = t >> 5;         // 8-way k split within block

    const int k0 = (kc * ns) >> 3, k1 = ((kc + 1) * ns) >> 3;
    float s = 0.f;
    for (int k = k0 + kq; k < k1; k += 8)
        s += ws[(size_t)k * SLICE + e];

    __shared__ float part[8][33];
    part[kq][t & 31] = s;
    __syncthreads();
    if (t < 32) {
        float v = 0.f;
        #pragma unroll
        for (int j = 0; j < 8; ++j) v += part[j][t];
        red2[kc * SLICE + ib * 32 + t] = v;
    }
    __syncthreads();                 // barrier drains vmem before t0 fences

    __shared__ int lastFlag;
    if (t == 0) {
        __threadfence();             // release red2 writes device-wide
        unsigned old = atomicAdd(cnt, 1u);
        lastFlag = (old == gridDim.x * gridDim.y - 1u);
    }
    __syncthreads();
    if (!lastFlag) return;
    __threadfence();                 // acquire

    // ---- epilogue in the last block
    __shared__ float red[SLICE];
    for (int e2 = t; e2 < SLICE; e2 += 256) {
        float v = 0.f;
        #pragma unroll
        for (int c = 0; c < 8; ++c) v += red2[c * SLICE + e2];
        red[e2] = v;
    }
    __syncthreads();

    __shared__ float spv[32], snv[32];
    if (t < 32)
        spv[t] = sqrtf(red[1024 + 64 + t]) /
                 (sqrtf(red[1024 + 96 + t]) * sqrtf(red[1024 + 128 + t]));
    __syncthreads();

    #pragma unroll
    for (int rep = 0; rep < 4; ++rep) {
        int idx = rep * 256 + t;
        int b = idx >> 5, d = idx & 31;
        float sim = 0.f;
        if (b != d)
            sim = sqrtf(red[idx]) /
                  (sqrtf(red[1024 + b]) * sqrtf(red[1024 + 32 + d]));
        #pragma unroll
        for (int off = 1; off < 32; off <<= 1) sim += __shfl_xor(sim, off);
        if ((t & 31) == 0) snv[b] = sim;
    }
    __syncthreads();

    float ls = 0.f;
    #pragma unroll
    for (int rep = 0; rep < 4; ++rep) {
        int idx = rep * 256 + t;
        int i = idx >> 5, j = idx & 31;
        ls += -logf(spv[j] / (spv[j] + snv[i]));
    }
    #pragma unroll
    for (int off = 1; off < 64; off <<= 1) ls += __shfl_xor(ls, off);
    __shared__ float wsum[4];
    if ((t & 63) == 0) wsum[t >> 6] = ls;
    __syncthreads();
    if (t == 0)
        out[0] = ((wsum[0] + wsum[1]) + (wsum[2] + wsum[3])) * (1.0f / 1024.0f);
}

extern "C" void kernel_launch(void* const* d_in, const int* in_sizes, int n_in,
                              void* d_out, int out_size, void* d_ws, size_t ws_size,
                              hipStream_t stream)
{
    const float* x1 = (const float*)d_in[0];
    const float* x2 = (const float*)d_in[1];
    const float* mk = (const float*)d_in[2];
    float* out = (float*)d_out;
    float* ws  = (float*)d_ws;

    long wsf = (long)(ws_size / sizeof(float));
    int ns = (int)((wsf - RED2N - 16) / SLICE);   // slices + red2 + counter fit
    if (ns > 1024) ns = 1024;
    if (ns < 1) ns = 1;

    cos_loss_main<<<ns, 256, 0, stream>>>(x1, x2, mk, ws, ns);
    cos_loss_tail<<<dim3(37, 8), 256, 0, stream>>>(ws, ns, out);
}

// Round 9
// 40.135 us; speedup vs baseline: 2.0845x; 2.0845x over previous
//
#include <hip/hip_runtime.h>
#include <math.h>

#define BATCH 32
#define HW (512*512)
#define TILE 256
#define NT (HW / TILE)     // 1024 tiles of 256 positions
#define RS 264             // shorts per LDS row: 256 data + 8 pad (132 dwords -> bank base 4*row)
#define SLICE 1184         // G[1024] + 5*32 row sums
#define RED2N 9472         // 8*1184 second-level partials

typedef __attribute__((ext_vector_type(8))) short bf16x8;
typedef __attribute__((ext_vector_type(4))) float f32x4;

__device__ __forceinline__ float fsigmoid(float x) {
    float e = __builtin_amdgcn_exp2f(-x * 1.44269504088896340736f);
    return __builtin_amdgcn_rcpf(1.0f + e);
}

// pack two f32 -> two bf16 (RNE) in one uint
__device__ __forceinline__ unsigned pkbf(float a, float b) {
    unsigned ua = __float_as_uint(a);
    ua = (ua + 0x7fffu + ((ua >> 16) & 1u)) >> 16;
    unsigned ub = __float_as_uint(b);
    ub = (ub + 0x7fffu + ((ub >> 16) & 1u)) & 0xffff0000u;
    return ua | ub;
}

__global__ __launch_bounds__(256, 4) void cos_loss_main(
    const float* __restrict__ x1, const float* __restrict__ x2,
    const float* __restrict__ mk, float* __restrict__ ws, int ns)
{
    __shared__ __align__(16) short smem[2 * BATCH * RS];   // 33792 B

    const int t = threadIdx.x;
    const int w = t >> 6;
    const int l = t & 63;

    if (blockIdx.x == 0 && t == 0) {
        unsigned* cnt = (unsigned*)(ws + (size_t)ns * SLICE + RED2N);
        *cnt = 0u;   // visible to tail via kernel-boundary ordering
    }

    short* S1 = smem;
    short* S2 = smem + BATCH * RS;

    const int arow = w * 8 + (l >> 3);   // phase-A row (one row per thread)
    const int a8   = (l & 7) * 4;        // phase-A float offset within 32-pos span
    const int q    = l >> 4;             // MFMA k-group 0..3
    const int fr   = l & 15;             // MFMA frag row/col

    f32x4 acc00 = {0.f,0.f,0.f,0.f}, acc01 = {0.f,0.f,0.f,0.f};
    f32x4 acc10 = {0.f,0.f,0.f,0.f}, acc11 = {0.f,0.f,0.f,0.f};
    float n1 = 0.f, n2 = 0.f, pp = 0.f, p1 = 0.f, p2 = 0.f;

    for (int tile = blockIdx.x; tile < NT; tile += ns) {
        const int base = tile * TILE;
        __syncthreads();   // prev-iter LDS readers done before overwrite

        // ---- Phase A: coalesced loads (8-lane group = 128B contiguous per row),
        //      sigmoid^2, fused row sums (mask binary), bf16 -> LDS
        const unsigned rbase = (unsigned)arow * HW + base + a8;
        short* w1 = S1 + arow * RS + a8;
        short* w2 = S2 + arow * RS + a8;
        #pragma unroll 2
        for (int it = 0; it < 8; ++it) {
            float4 v1 = *(const float4*)(x1 + rbase + it * 32);
            float4 v2 = *(const float4*)(x2 + rbase + it * 32);
            float4 vm = *(const float4*)(mk + rbase + it * 32);
            float4 q1, q2;
            { float s = fsigmoid(v1.x); q1.x = s*s; }
            { float s = fsigmoid(v1.y); q1.y = s*s; }
            { float s = fsigmoid(v1.z); q1.z = s*s; }
            { float s = fsigmoid(v1.w); q1.w = s*s; }
            { float s = fsigmoid(v2.x); q2.x = s*s; }
            { float s = fsigmoid(v2.y); q2.y = s*s; }
            { float s = fsigmoid(v2.z); q2.z = s*s; }
            { float s = fsigmoid(v2.w); q2.w = s*s; }
            n1 += (q1.x + q1.y) + (q1.z + q1.w);
            n2 += (q2.x + q2.y) + (q2.z + q2.w);
            p1 = fmaf(vm.x, q1.x, fmaf(vm.y, q1.y, fmaf(vm.z, q1.z, fmaf(vm.w, q1.w, p1))));
            p2 = fmaf(vm.x, q2.x, fmaf(vm.y, q2.y, fmaf(vm.z, q2.z, fmaf(vm.w, q2.w, p2))));
            pp = fmaf(vm.x, q1.x*q2.x, fmaf(vm.y, q1.y*q2.y,
                 fmaf(vm.z, q1.z*q2.z, fmaf(vm.w, q1.w*q2.w, pp))));
            uint2 u1; u1.x = pkbf(q1.x, q1.y); u1.y = pkbf(q1.z, q1.w);
            uint2 u2; u2.x = pkbf(q2.x, q2.y); u2.y = pkbf(q2.z, q2.w);
            *(uint2*)(w1 + it * 32) = u1;
            *(uint2*)(w2 + it * 32) = u2;
        }
        __syncthreads();

        // ---- Phase B: wave w covers K = [64w, 64w+64); 2x2 tiles of 16x16x32 MFMA.
        // A,B frags use identical row-independent addressing -> k-permutation cancels.
        const int kb = fr * RS + w * 64;
        #pragma unroll
        for (int ks = 0; ks < 2; ++ks) {
            bf16x8 a0 = *(const bf16x8*)(S1 + kb + ks * 32 + q * 8);
            bf16x8 a1 = *(const bf16x8*)(S1 + kb + 16 * RS + ks * 32 + q * 8);
            bf16x8 b0 = *(const bf16x8*)(S2 + kb + ks * 32 + q * 8);
            bf16x8 b1 = *(const bf16x8*)(S2 + kb + 16 * RS + ks * 32 + q * 8);
            acc00 = __builtin_amdgcn_mfma_f32_16x16x32_bf16(a0, b0, acc00, 0, 0, 0);
            acc01 = __builtin_amdgcn_mfma_f32_16x16x32_bf16(a0, b1, acc01, 0, 0, 0);
            acc10 = __builtin_amdgcn_mfma_f32_16x16x32_bf16(a1, b0, acc10, 0, 0, 0);
            acc11 = __builtin_amdgcn_mfma_f32_16x16x32_bf16(a1, b1, acc11, 0, 0, 0);
        }
    }

    float* slice = ws + (size_t)blockIdx.x * SLICE;

    // ---- row sums: 8 lanes (l&7) share arow; reduce and store directly
    #pragma unroll
    for (int off = 1; off < 8; off <<= 1) {
        n1 += __shfl_xor(n1, off);
        n2 += __shfl_xor(n2, off);
        pp += __shfl_xor(pp, off);
        p1 += __shfl_xor(p1, off);
        p2 += __shfl_xor(p2, off);
    }
    if ((l & 7) == 0) {
        slice[1024 +       arow] = n1;
        slice[1024 +  32 + arow] = n2;
        slice[1024 +  64 + arow] = pp;
        slice[1024 +  96 + arow] = p1;
        slice[1024 + 128 + arow] = p2;
    }

    // ---- G merge across 4 waves via LDS (staging buffers now dead)
    __syncthreads();
    float* Gm = (float*)smem;   // [4][1024] = 16 KB
    {
        const int gb = w * 1024;
        #pragma unroll
        for (int r2 = 0; r2 < 4; ++r2) {
            // C/D layout (m89): col = lane&15, row = (lane>>4)*4 + reg
            Gm[gb + (     q*4 + r2) * 32 +      fr] = acc00[r2];
            Gm[gb + (     q*4 + r2) * 32 + 16 + fr] = acc01[r2];
            Gm[gb + (16 + q*4 + r2) * 32 +      fr] = acc10[r2];
            Gm[gb + (16 + q*4 + r2) * 32 + 16 + fr] = acc11[r2];
        }
    }
    __syncthreads();
    #pragma unroll
    for (int r2 = 0; r2 < 4; ++r2) {
        int e = r2 * 256 + t;
        slice[e] = ((Gm[e] + Gm[1024 + e]) + (Gm[2048 + e] + Gm[3072 + e]));
    }
}

// grid (37, 8): block (ib, kc) sums slices k in [kc*ns/8,(kc+1)*ns/8) for
// 32 elements; last-done block reduces the 8 partials and runs the epilogue.
__global__ __launch_bounds__(256) void cos_loss_tail(
    float* __restrict__ ws, int ns, float* __restrict__ out)
{
    float* red2 = ws + (size_t)ns * SLICE;          // [8][1184]
    unsigned* cnt = (unsigned*)(red2 + RED2N);

    const int t  = threadIdx.x;
    const int ib = blockIdx.x;     // 0..36
    const int kc = blockIdx.y;     // 0..7
    const int e  = ib * 32 + (t & 31);
    const int kq = t >> 5;         // 8-way k split within block

    const int k0 = (kc * ns) >> 3, k1 = ((kc + 1) * ns) >> 3;
    float s = 0.f;
    for (int k = k0 + kq; k < k1; k += 8)
        s += ws[(size_t)k * SLICE + e];

    __shared__ float part[8][33];
    part[kq][t & 31] = s;
    __syncthreads();
    if (t < 32) {
        float v = 0.f;
        #pragma unroll
        for (int j = 0; j < 8; ++j) v += part[j][t];
        red2[kc * SLICE + ib * 32 + t] = v;
    }
    __syncthreads();                 // barrier drains vmem before t0 fences

    __shared__ int lastFlag;
    if (t == 0) {
        __threadfence();             // release red2 writes device-wide
        unsigned old = atomicAdd(cnt, 1u);
        lastFlag = (old == gridDim.x * gridDim.y - 1u);
    }
    __syncthreads();
    if (!lastFlag) return;
    __threadfence();                 // acquire

    // ---- epilogue in the last block
    __shared__ float red[SLICE];
    for (int e2 = t; e2 < SLICE; e2 += 256) {
        float v = 0.f;
        #pragma unroll
        for (int c = 0; c < 8; ++c) v += red2[c * SLICE + e2];
        red[e2] = v;
    }
    __syncthreads();

    __shared__ float spv[32], snv[32];
    if (t < 32)
        spv[t] = sqrtf(red[1024 + 64 + t]) /
                 (sqrtf(red[1024 + 96 + t]) * sqrtf(red[1024 + 128 + t]));
    __syncthreads();

    #pragma unroll
    for (int rep = 0; rep < 4; ++rep) {
        int idx = rep * 256 + t;
        int b = idx >> 5, d = idx & 31;
        float sim = 0.f;
        if (b != d)
            sim = sqrtf(red[idx]) /
                  (sqrtf(red[1024 + b]) * sqrtf(red[1024 + 32 + d]));
        #pragma unroll
        for (int off = 1; off < 32; off <<= 1) sim += __shfl_xor(sim, off);
        if ((t & 31) == 0) snv[b] = sim;
    }
    __syncthreads();

    float ls = 0.f;
    #pragma unroll
    for (int rep = 0; rep < 4; ++rep) {
        int idx = rep * 256 + t;
        int i = idx >> 5, j = idx & 31;
        ls += -logf(spv[j] / (spv[j] + snv[i]));
    }
    #pragma unroll
    for (int off = 1; off < 64; off <<= 1) ls += __shfl_xor(ls, off);
    __shared__ float wsum[4];
    if ((t & 63) == 0) wsum[t >> 6] = ls;
    __syncthreads();
    if (t == 0)
        out[0] = ((wsum[0] + wsum[1]) + (wsum[2] + wsum[3])) * (1.0f / 1024.0f);
}

extern "C" void kernel_launch(void* const* d_in, const int* in_sizes, int n_in,
                              void* d_out, int out_size, void* d_ws, size_t ws_size,
                              hipStream_t stream)
{
    const float* x1 = (const float*)d_in[0];
    const float* x2 = (const float*)d_in[1];
    const float* mk = (const float*)d_in[2];
    float* out = (float*)d_out;
    float* ws  = (float*)d_ws;

    long wsf = (long)(ws_size / sizeof(float));
    int ns = (int)((wsf - RED2N - 16) / SLICE);   // slices + red2 + counter fit
    if (ns > NT) ns = NT;
    if (ns < 1) ns = 1;

    cos_loss_main<<<ns, 256, 0, stream>>>(x1, x2, mk, ws, ns);
    cos_loss_tail<<<dim3(37, 8), 256, 0, stream>>>(ws, ns, out);
}